// Round 17
// baseline (121.007 us; speedup 1.0000x reference)
//
#include <hip/hip_runtime.h>
#include <hip/hip_bf16.h>
#include <cstdint>

#define HW 128
#define HWP 132                    // padded row stride (words): taps 4 banks apart, uint4-aligned writes
#define MASK_ELEMS (HW * HW)
#define TILE_WORDS (HW * HWP)      // 16896 words = 66KB per tile
#define SBLK 1024                  // sampler block size (16 waves)
#define NBLK 256                   // sampler grid (1 block/CU via ~135KB LDS)
#define NWAVE (SBLK / 64)

typedef unsigned short ushort_t;
typedef __attribute__((ext_vector_type(4))) unsigned short ushort4_t;
typedef __attribute__((ext_vector_type(8))) short short8;
typedef __attribute__((ext_vector_type(4))) float f32x4;

__device__ __forceinline__ float asf(unsigned int u) {
    union { unsigned int i; float f; } c;
    c.i = u;
    return c.f;
}
__device__ __forceinline__ ushort_t f2bf(float f) {
    union { float f; unsigned int i; } c;
    c.f = f;
    unsigned int r = c.i + 0x7FFFu + ((c.i >> 16) & 1u);  // RNE
    return (ushort_t)(r >> 16);
}
__device__ __forceinline__ unsigned pack2(float a, float b) {
    return (unsigned)f2bf(a) | ((unsigned)f2bf(b) << 16);
}

// Packed-pair dot: w = (bf16 w0, bf16 w1), t = (bf16 t0, bf16 t1) -> c + w0*t0 + w1*t1.
#if __has_builtin(__builtin_amdgcn_fdot2_f32_bf16)
typedef __bf16 bf16x2_t __attribute__((ext_vector_type(2)));
__device__ __forceinline__ float tap_dot(unsigned w, unsigned t, float c) {
    return __builtin_amdgcn_fdot2_f32_bf16(__builtin_bit_cast(bf16x2_t, w),
                                           __builtin_bit_cast(bf16x2_t, t), c, false);
}
#else
__device__ __forceinline__ float tap_dot(unsigned w, unsigned t, float c) {
    return c + asf(w << 16) * asf(t << 16)
             + asf(w & 0xffff0000u) * asf(t & 0xffff0000u);
}
#endif

// LDS-visibility-only barrier: NO vmcnt drain (keeps stage loads in flight).
#define LDS_BARRIER()                                         \
    do {                                                      \
        asm volatile("s_waitcnt lgkmcnt(0)" ::: "memory");    \
        __builtin_amdgcn_s_barrier();                         \
    } while (0)

// Per-point bilinear setup: PADDED base b = by*132+bx (bx<=126, by<=126); taps are
// lm[b] (pair x,x+1 of row by) and lm[b+132] (pair of row by+1) -> banks differ by 4.
struct PMeta { int b; unsigned u0, u1; };
__device__ __forceinline__ PMeta prep_point(float cx, float cy) {
    float x = cx * (float)HW - 0.5f;
    float y = cy * (float)HW - 0.5f;
    float x0f = floorf(x), y0f = floorf(y);
    float wx1 = x - x0f, wy1 = y - y0f;
    float wx0 = 1.f - wx1, wy0 = 1.f - wy1;
    int x0 = (int)x0f, y0 = (int)y0f;
    float wxA = (x0 >= 0) ? wx0 : wx1;
    float wxB = (x0 >= 0 && x0 < HW - 1) ? wx1 : 0.f;
    float wyA = (y0 >= 0) ? wy0 : wy1;
    float wyB = (y0 >= 0 && y0 < HW - 1) ? wy1 : 0.f;
    int bx = max(x0, 0), by = max(y0, 0);
    if (bx > HW - 2) { bx = HW - 2; wxB = wxA; wxA = 0.f; }
    if (by > HW - 2) { by = HW - 2; wyB = wyA; wyA = 0.f; }
    PMeta m;
    m.b = by * HWP + bx;
    m.u0 = pack2(wxA * wyA, wxB * wyA);
    m.u1 = pack2(wxA * wyB, wxB * wyB);
    return m;
}

// ---------- kernel 1: persistent fused sampler — ONE barrier per mask, no serial reduce ---
// r10-r16 ledger: ~9us/mask invariant under staging/occupancy/conflict changes. The only
// constants were 2 barriers + serial tid0 reduce per mask. This round: single barrier per
// iteration (double-buffer makes it sufficient: it separates last iter's reads of buf[~k]
// from this iter's pack-writes AND last iter's pack of buf[k] from this iter's reads);
// per-wave sums go straight to global spart[16][NM] (deterministic per (wave,mask)).
__global__ __launch_bounds__(SBLK) void ksamp_all(
        const float* __restrict__ pmask, const float* __restrict__ tmasks,
        const float* __restrict__ coords,
        ushort_t* __restrict__ S, ushort_t* __restrict__ tsamp,
        float* __restrict__ spart,
        const int* __restrict__ lvl, int N, int T, int P) {
    if (*lvl >= 2) return;
    __shared__ unsigned buf[2][TILE_WORDS];  // 2 x 66KB padded packed-pair tiles
    __shared__ int4  tmi4[64];               // tail-quad meta (3KB)
    __shared__ uint4 tma[64], tmb[64];
    const int tid = threadIdx.x;
    const int lane = tid & 63;
    const int wid = tid >> 6;
    const int NM = N + T;
    const int nq = P >> 2;
    const int ntail = nq - 3 * SBLK;         // 64 for P=12544

    // ---- dense meta: 3 quads/thread computed from coords (36 VGPR) ----
    int4 idr[3];
    uint4 war[3], wbr[3];
    #pragma unroll
    for (int it = 0; it < 3; ++it) {
        int q = it * SBLK + tid;
        if (q < nq) {
            float4 ca = ((const float4*)coords)[2 * q];
            float4 cb = ((const float4*)coords)[2 * q + 1];
            PMeta m0 = prep_point(ca.x, ca.y), m1 = prep_point(ca.z, ca.w);
            PMeta m2 = prep_point(cb.x, cb.y), m3 = prep_point(cb.z, cb.w);
            idr[it] = make_int4(m0.b, m1.b, m2.b, m3.b);
            war[it] = make_uint4(m0.u0, m0.u1, m1.u0, m1.u1);
            wbr[it] = make_uint4(m2.u0, m2.u1, m3.u0, m3.u1);
        } else {
            idr[it] = make_int4(0, 0, 0, 0);
            war[it] = make_uint4(0, 0, 0, 0);
            wbr[it] = make_uint4(0, 0, 0, 0);
        }
    }
    // ---- tail meta -> LDS (computed once; visible after first barrier) ----
    if (ntail > 0 && tid < ntail && tid < 64) {
        int q = 3 * SBLK + tid;
        float4 ca = ((const float4*)coords)[2 * q];
        float4 cb = ((const float4*)coords)[2 * q + 1];
        PMeta m0 = prep_point(ca.x, ca.y), m1 = prep_point(ca.z, ca.w);
        PMeta m2 = prep_point(cb.x, cb.y), m3 = prep_point(cb.z, cb.w);
        tmi4[tid] = make_int4(m0.b, m1.b, m2.b, m3.b);
        tma[tid] = make_uint4(m0.u0, m0.u1, m1.u0, m1.u1);
        tmb[tid] = make_uint4(m2.u0, m2.u1, m3.u0, m3.u1);
    }

    auto mptr = [&](int mi) -> const float* {
        return (mi < N) ? pmask + (size_t)mi * MASK_ELEMS
                        : tmasks + (size_t)(mi - N) * MASK_ELEMS;
    };

    const int b = blockIdx.x;
    const int rounds = (NM - b + NBLK - 1) / NBLK;   // 10 for NM=2560
    if (rounds <= 0) return;

    float4 rS[4];
    float nxr[4];                             // lane-63-only next-element values
    auto load_mask = [&](const float* g) {
        #pragma unroll
        for (int j = 0; j < 4; ++j) {
            int o = j * (SBLK * 4) + tid * 4;
            rS[j] = *(const float4*)(g + o);
            nxr[j] = (lane == 63) ? g[min(o + 4, MASK_ELEMS - 1)] : 0.f;
        }
    };
    auto pack_mask = [&](unsigned* l) {
        #pragma unroll
        for (int j = 0; j < 4; ++j) {
            int o = j * (SBLK * 4) + tid * 4;      // linear word index (4 words, one row)
            float4 v = rS[j];
            float nx = __shfl_down(v.x, 1);
            if (lane == 63) nx = nxr[j];
            int row = o >> 7, col = o & 127;
            uint4 e = make_uint4(pack2(v.x, v.y), pack2(v.y, v.z),
                                 pack2(v.z, v.w), pack2(v.w, nx));
            *(uint4*)&l[row * HWP + col] = e;      // 16B-aligned (132*row + col, col%4==0)
        }
    };

    load_mask(mptr(b));
    pack_mask(buf[0]);
    if (rounds > 1) load_mask(mptr(b + NBLK));

    for (int k = 0; k < rounds; ++k) {
        LDS_BARRIER();   // the ONLY barrier: orders prev reads of buf[~k] vs pack below,
                         // and prev pack of buf[k] vs sample reads below.
        if (k + 1 < rounds) {
            pack_mask(buf[(k + 1) & 1]);                      // mask k+1 -> other buffer
            if (k + 2 < rounds) load_mask(mptr(b + (k + 2) * NBLK));  // k+2 in flight
        }
        const unsigned* lm = buf[k & 1];
        const int mi = b + k * NBLK;
        const bool sig = (mi < N);
        ushort4_t* o4 = sig ? (ushort4_t*)(S + (size_t)mi * P)
                            : (ushort4_t*)(tsamp + (size_t)(mi - N) * P);
        float sum = 0.f;

        auto do_quad = [&](int4 id, uint4 wa4, uint4 wb4, int q) {
            float v[4];
            int bi[4] = {id.x, id.y, id.z, id.w};
            unsigned ua[4] = {wa4.x, wa4.z, wb4.x, wb4.z};
            unsigned ub[4] = {wa4.y, wa4.w, wb4.y, wb4.w};
            #pragma unroll
            for (int p2 = 0; p2 < 4; ++p2) {
                int bb = bi[p2];
                unsigned r0 = lm[bb];         // pair (m[y,x], m[y,x+1])
                unsigned r1 = lm[bb + HWP];   // pair of row y+1, bank +4
                float vv = tap_dot(ua[p2], r0, tap_dot(ub[p2], r1, 0.f));
                if (sig) vv = __builtin_amdgcn_rcpf(1.f + __expf(-vv));
                v[p2] = vv;
            }
            ushort4_t o = {f2bf(v[0]), f2bf(v[1]), f2bf(v[2]), f2bf(v[3])};
            o4[q] = o;
            sum += (v[0] + v[1]) + (v[2] + v[3]);
        };

        #pragma unroll
        for (int it = 0; it < 3; ++it) {
            int q = it * SBLK + tid;
            if (q < nq) do_quad(idr[it], war[it], wbr[it], q);
        }
        if (ntail > 0 && ntail <= 64) {                       // balanced tail (1 per 16 lanes)
            int tq = tid >> 4;
            if (((tid & 15) == 0) && tq < ntail)
                do_quad(tmi4[tq], tma[tq], tmb[tq], 3 * SBLK + tq);
        }

        #pragma unroll
        for (int m2 = 32; m2 > 0; m2 >>= 1) sum += __shfl_xor(sum, m2, 64);
        if (lane == 0) spart[(size_t)wid * NM + mi] = sum;    // no block reduce, no 2nd barrier
    }
}

// ---------- kernel 2: MFMA split-K GEMM: Cpart[ks][n][t] = sum_k S[n,k]*Tm[t,k] ----------
#define LDF(Aarr, Barr, kof)                                                              \
    do {                                                                                  \
        _Pragma("unroll") for (int m_ = 0; m_ < 3; ++m_)                                  \
            Aarr[m_] = *(const short8*)(pa + (size_t)m_ * 16 * P + (kof));                \
        _Pragma("unroll") for (int j_ = 0; j_ < 5; ++j_)                                  \
            Barr[j_] = *(const short8*)(pb + (size_t)j_ * 16 * P + (kof));                \
    } while (0)

#define FMAS(Aarr, Barr)                                                                  \
    do {                                                                                  \
        _Pragma("unroll") for (int m_ = 0; m_ < 3; ++m_) {                                \
            _Pragma("unroll") for (int j_ = 0; j_ < 5; ++j_)                              \
                acc[m_][j_] = __builtin_amdgcn_mfma_f32_16x16x32_bf16(                    \
                    Aarr[m_], Barr[j_], acc[m_][j_], 0, 0, 0);                            \
        }                                                                                 \
    } while (0)

__global__ __launch_bounds__(256) void kgemm(const ushort_t* __restrict__ S,
                                             const ushort_t* __restrict__ Tm,
                                             float* __restrict__ Cpart,
                                             const int* __restrict__ lvl,
                                             int N, int T, int P, int nsteps) {
    if (*lvl >= 2) return;
    int tid = threadIdx.x;
    int wid = tid >> 6, lane = tid & 63;
    int wm = wid >> 1, wt = wid & 1;
    int r = lane & 15, g = lane >> 4;
    int n0 = blockIdx.x * 96 + wm * 48;
    int t0 = wt * 80;
    size_t k0 = (size_t)blockIdx.y * nsteps * 32 + g * 8;
    const ushort_t* pa = S + (size_t)(n0 + r) * P + k0;
    const ushort_t* pb = Tm + (size_t)(t0 + r) * P + k0;

    f32x4 acc[3][5];
    #pragma unroll
    for (int m2 = 0; m2 < 3; ++m2)
        #pragma unroll
        for (int j2 = 0; j2 < 5; ++j2) acc[m2][j2] = (f32x4){0.f, 0.f, 0.f, 0.f};

    short8 a0[3], b0[5], a1[3], b1[5];
    LDF(a0, b0, 0);
    int ks = 0;
    for (; ks + 2 < nsteps; ks += 2) {
        LDF(a1, b1, (ks + 1) * 32);
        FMAS(a0, b0);
        LDF(a0, b0, (ks + 2) * 32);
        FMAS(a1, b1);
    }
    LDF(a1, b1, (ks + 1) * 32);
    FMAS(a0, b0);
    FMAS(a1, b1);

    size_t cb = (size_t)blockIdx.y * N * T;
    #pragma unroll
    for (int m2 = 0; m2 < 3; ++m2)
        #pragma unroll
        for (int j2 = 0; j2 < 5; ++j2)
            #pragma unroll
            for (int q = 0; q < 4; ++q) {
                int row = n0 + m2 * 16 + g * 4 + q;
                int col = t0 + j2 * 16 + r;
                Cpart[cb + (size_t)row * T + col] = acc[m2][j2][q];
            }
}

// ---------- kernel 3: epilogue (folds the 16 per-wave sum partials) ----------
__global__ void kfinal(const float* __restrict__ logits, const float* __restrict__ opts,
                       const float* __restrict__ tpts, const float* __restrict__ Cpart,
                       const float* __restrict__ spart,
                       const int* __restrict__ lvl, float* __restrict__ out,
                       int N, int T, int nks) {
    int idx = blockIdx.x * 256 + threadIdx.x;
    if (idx >= N * T) return;
    int n = idx / T, t = idx - n * T;

    float lg = logits[n];
    float p = 1.f / (1.f + __expf(-lg));
    float pos = 0.25f * (1.f - p) * (1.f - p) * (-logf(p + 1e-8f));
    float neg = 0.75f * p * p * (-logf(1.f - p + 1e-8f));
    float ccls = pos - neg;

    float kp = 0.f;
    const float4* a4 = (const float4*)(opts + (size_t)n * 32);
    const float4* b4 = (const float4*)(tpts + (size_t)t * 32);
    #pragma unroll
    for (int j = 0; j < 8; ++j) {
        float4 a = a4[j], b = b4[j];
        kp += fabsf(a.x - b.x) + fabsf(a.y - b.y) + fabsf(a.z - b.z) + fabsf(a.w - b.w);
    }

    float dice = 0.f;
    if (*lvl < 2) {
        float dot = 0.f;
        for (int ks = 0; ks < nks; ++ks) dot += Cpart[(size_t)ks * N * T + idx];
        int NM = N + T;
        float sn = 0.f, st = 0.f;
        #pragma unroll
        for (int w2 = 0; w2 < NWAVE; ++w2) {
            sn += spart[(size_t)w2 * NM + n];
            st += spart[(size_t)w2 * NM + N + t];
        }
        dice = 1.f - (2.f * dot + 1.f) / (sn + st + 1.f);
    }
    out[idx] = 2.f * ccls + 5.f * kp + 5.f * dice;
}

extern "C" void kernel_launch(void* const* d_in, const int* in_sizes, int n_in,
                              void* d_out, int out_size, void* d_ws, size_t ws_size,
                              hipStream_t stream) {
    const float* logits = (const float*)d_in[0];
    const float* cpts   = (const float*)d_in[1];
    const float* pmask  = (const float*)d_in[2];
    const float* tpts   = (const float*)d_in[3];
    const float* tmasks = (const float*)d_in[4];
    const float* coords = (const float*)d_in[5];
    const int*   lvl    = (const int*)d_in[6];
    float* out = (float*)d_out;

    int N = in_sizes[0];        // 2400
    int T = in_sizes[3] / 32;   // 160
    int P = in_sizes[5] / 2;    // 12544
    int NM = N + T;

    char* w = (char*)d_ws;
    auto alloc = [&](size_t bytes) {
        char* r = w;
        w += (bytes + 255) & ~(size_t)255;
        return r;
    };
    ushort_t* tsamp = (ushort_t*)alloc((size_t)T * P * 2);
    ushort_t* S     = (ushort_t*)alloc((size_t)N * P * 2);
    float*    spart = (float*)alloc((size_t)NWAVE * NM * 4);
    size_t base_bytes = (size_t)(w - (char*)d_ws);

    int nks = 14;
    if (base_bytes + (size_t)nks * N * T * 4 > ws_size) nks = 7;
    int nsteps = (P / 32) / nks;
    float* Cpart = (float*)alloc((size_t)nks * N * T * 4);

    ksamp_all<<<NBLK, SBLK, 0, stream>>>(pmask, tmasks, coords, S, tsamp,
                                         spart, lvl, N, T, P);
    kgemm<<<dim3(N / 96, nks), 256, 0, stream>>>(S, tsamp, Cpart, lvl, N, T, P, nsteps);
    kfinal<<<(N * T + 255) / 256, 256, 0, stream>>>(logits, cpts, tpts, Cpart, spart,
                                                    lvl, out, N, T, nks);
}

// Round 18
// 116.190 us; speedup vs baseline: 1.0415x; 1.0415x over previous
//
#include <hip/hip_runtime.h>
#include <hip/hip_bf16.h>
#include <cstdint>

#define HW 128
#define HWP 132                    // padded row stride (words): taps 4 banks apart, uint4-aligned writes
#define MASK_ELEMS (HW * HW)
#define TILE_WORDS (HW * HWP)      // 16896 words = 66KB per tile
#define SBLK 1024                  // sampler block size (16 waves)
#define NBLK 256                   // sampler grid (1 block/CU via ~135KB LDS)

typedef unsigned short ushort_t;
typedef __attribute__((ext_vector_type(4))) unsigned short ushort4_t;
typedef __attribute__((ext_vector_type(8))) short short8;
typedef __attribute__((ext_vector_type(4))) float f32x4;

__device__ __forceinline__ float asf(unsigned int u) {
    union { unsigned int i; float f; } c;
    c.i = u;
    return c.f;
}
__device__ __forceinline__ ushort_t f2bf(float f) {          // RNE (tile + weights)
    union { float f; unsigned int i; } c;
    c.f = f;
    unsigned int r = c.i + 0x7FFFu + ((c.i >> 16) & 1u);
    return (ushort_t)(r >> 16);
}
__device__ __forceinline__ ushort_t f2bf_t(float f) {        // truncating (outputs only)
    union { float f; unsigned int i; } c;
    c.f = f;
    return (ushort_t)(c.i >> 16);
}
__device__ __forceinline__ unsigned pack2(float a, float b) {
    return (unsigned)f2bf(a) | ((unsigned)f2bf(b) << 16);
}

// Minimal-op sigmoid: 1/(1+e^-v) = rcp(1 + 2^(v * -log2e))
#if __has_builtin(__builtin_amdgcn_exp2f)
__device__ __forceinline__ float fast_sigmoid(float v) {
    return __builtin_amdgcn_rcpf(1.f + __builtin_amdgcn_exp2f(v * -1.442695041f));
}
#else
__device__ __forceinline__ float fast_sigmoid(float v) {
    return __builtin_amdgcn_rcpf(1.f + __expf(-v));
}
#endif

// Packed-pair dot: w = (bf16 w0, bf16 w1), t = (bf16 t0, bf16 t1) -> c + w0*t0 + w1*t1.
#if __has_builtin(__builtin_amdgcn_fdot2_f32_bf16)
typedef __bf16 bf16x2_t __attribute__((ext_vector_type(2)));
__device__ __forceinline__ float tap_dot(unsigned w, unsigned t, float c) {
    return __builtin_amdgcn_fdot2_f32_bf16(__builtin_bit_cast(bf16x2_t, w),
                                           __builtin_bit_cast(bf16x2_t, t), c, false);
}
#else
__device__ __forceinline__ float tap_dot(unsigned w, unsigned t, float c) {
    return c + asf(w << 16) * asf(t << 16)
             + asf(w & 0xffff0000u) * asf(t & 0xffff0000u);
}
#endif

// LDS-visibility-only barrier: NO vmcnt drain (keeps stage loads in flight).
#define LDS_BARRIER()                                         \
    do {                                                      \
        asm volatile("s_waitcnt lgkmcnt(0)" ::: "memory");    \
        __builtin_amdgcn_s_barrier();                         \
    } while (0)

// Per-point bilinear setup: PADDED base b = by*132+bx (bx<=126, by<=126); taps are
// lm[b] (pair x,x+1 of row by) and lm[b+132] (pair of row by+1).
struct PMeta { int b; unsigned u0, u1; };
__device__ __forceinline__ PMeta prep_point(float cx, float cy) {
    float x = cx * (float)HW - 0.5f;
    float y = cy * (float)HW - 0.5f;
    float x0f = floorf(x), y0f = floorf(y);
    float wx1 = x - x0f, wy1 = y - y0f;
    float wx0 = 1.f - wx1, wy0 = 1.f - wy1;
    int x0 = (int)x0f, y0 = (int)y0f;
    float wxA = (x0 >= 0) ? wx0 : wx1;
    float wxB = (x0 >= 0 && x0 < HW - 1) ? wx1 : 0.f;
    float wyA = (y0 >= 0) ? wy0 : wy1;
    float wyB = (y0 >= 0 && y0 < HW - 1) ? wy1 : 0.f;
    int bx = max(x0, 0), by = max(y0, 0);
    if (bx > HW - 2) { bx = HW - 2; wxB = wxA; wxA = 0.f; }
    if (by > HW - 2) { by = HW - 2; wyB = wyA; wyA = 0.f; }
    PMeta m;
    m.b = by * HWP + bx;
    m.u0 = pack2(wxA * wyA, wxB * wyA);
    m.u1 = pack2(wxA * wyB, wxB * wyB);
    return m;
}

// ---------- kernel 1: persistent fused sampler (r16 skeleton + aligned writes + VALU cuts) -
__global__ __launch_bounds__(SBLK) void ksamp_all(
        const float* __restrict__ pmask, const float* __restrict__ tmasks,
        const float* __restrict__ coords,
        ushort_t* __restrict__ S, ushort_t* __restrict__ tsamp,
        float* __restrict__ ssum, float* __restrict__ tsum,
        const int* __restrict__ lvl, int N, int T, int P) {
    if (*lvl >= 2) return;
    __shared__ unsigned buf[2][TILE_WORDS];  // 2 x 66KB padded packed-pair tiles
    __shared__ float wred[2][SBLK / 64];
    __shared__ int4  tmi4[64];               // tail-quad meta (3KB)
    __shared__ uint4 tma[64], tmb[64];
    const int tid = threadIdx.x;
    const int lane = tid & 63;
    const int NM = N + T;
    const int nq = P >> 2;
    const int ntail = nq - 3 * SBLK;         // 64 for P=12544

    // ---- dense meta: 3 quads/thread computed from coords (36 VGPR) ----
    int4 idr[3];
    uint4 war[3], wbr[3];
    #pragma unroll
    for (int it = 0; it < 3; ++it) {
        int q = it * SBLK + tid;
        if (q < nq) {
            float4 ca = ((const float4*)coords)[2 * q];
            float4 cb = ((const float4*)coords)[2 * q + 1];
            PMeta m0 = prep_point(ca.x, ca.y), m1 = prep_point(ca.z, ca.w);
            PMeta m2 = prep_point(cb.x, cb.y), m3 = prep_point(cb.z, cb.w);
            idr[it] = make_int4(m0.b, m1.b, m2.b, m3.b);
            war[it] = make_uint4(m0.u0, m0.u1, m1.u0, m1.u1);
            wbr[it] = make_uint4(m2.u0, m2.u1, m3.u0, m3.u1);
        } else {
            idr[it] = make_int4(0, 0, 0, 0);
            war[it] = make_uint4(0, 0, 0, 0);
            wbr[it] = make_uint4(0, 0, 0, 0);
        }
    }
    // ---- tail meta -> LDS (computed once; visible after first barrier) ----
    if (ntail > 0 && tid < ntail && tid < 64) {
        int q = 3 * SBLK + tid;
        float4 ca = ((const float4*)coords)[2 * q];
        float4 cb = ((const float4*)coords)[2 * q + 1];
        PMeta m0 = prep_point(ca.x, ca.y), m1 = prep_point(ca.z, ca.w);
        PMeta m2 = prep_point(cb.x, cb.y), m3 = prep_point(cb.z, cb.w);
        tmi4[tid] = make_int4(m0.b, m1.b, m2.b, m3.b);
        tma[tid] = make_uint4(m0.u0, m0.u1, m1.u0, m1.u1);
        tmb[tid] = make_uint4(m2.u0, m2.u1, m3.u0, m3.u1);
    }

    auto mptr = [&](int mi) -> const float* {
        return (mi < N) ? pmask + (size_t)mi * MASK_ELEMS
                        : tmasks + (size_t)(mi - N) * MASK_ELEMS;
    };

    const int b = blockIdx.x;
    const int rounds = (NM - b + NBLK - 1) / NBLK;   // 10 for NM=2560
    if (rounds <= 0) return;

    float4 rS[4];
    float nxr[4];                             // lane-63-only next-element values
    auto load_mask = [&](const float* g) {
        #pragma unroll
        for (int j = 0; j < 4; ++j) {
            int o = j * (SBLK * 4) + tid * 4;
            rS[j] = *(const float4*)(g + o);
            nxr[j] = (lane == 63) ? g[min(o + 4, MASK_ELEMS - 1)] : 0.f;
        }
    };
    auto pack_mask = [&](unsigned* l) {
        #pragma unroll
        for (int j = 0; j < 4; ++j) {
            int o = j * (SBLK * 4) + tid * 4;      // linear word index (4 words, one row)
            float4 v = rS[j];
            float nx = __shfl_down(v.x, 1);
            if (lane == 63) nx = nxr[j];
            int row = o >> 7, col = o & 127;
            uint4 e = make_uint4(pack2(v.x, v.y), pack2(v.y, v.z),
                                 pack2(v.z, v.w), pack2(v.w, nx));
            *(uint4*)&l[row * HWP + col] = e;      // 16B-aligned (132*row + col, col%4==0)
        }
    };

    load_mask(mptr(b));
    pack_mask(buf[0]);
    if (rounds > 1) load_mask(mptr(b + NBLK));

    for (int k = 0; k < rounds; ++k) {
        LDS_BARRIER();   // orders prev reads of buf[k&1^1] vs pack below, and prev pack
                         // of buf[k&1] vs sample reads below (double-buffer => sufficient)
        if (k + 1 < rounds) {
            pack_mask(buf[(k + 1) & 1]);                      // mask k+1 -> other buffer
            if (k + 2 < rounds) load_mask(mptr(b + (k + 2) * NBLK));  // k+2 in flight
        }
        const unsigned* lm = buf[k & 1];
        const int mi = b + k * NBLK;
        const bool sig = (mi < N);
        ushort4_t* o4 = sig ? (ushort4_t*)(S + (size_t)mi * P)
                            : (ushort4_t*)(tsamp + (size_t)(mi - N) * P);
        float sum = 0.f;

        auto do_quad = [&](int4 id, uint4 wa4, uint4 wb4, int q) {
            float v[4];
            int bi[4] = {id.x, id.y, id.z, id.w};
            unsigned ua[4] = {wa4.x, wa4.z, wb4.x, wb4.z};
            unsigned ub[4] = {wa4.y, wa4.w, wb4.y, wb4.w};
            #pragma unroll
            for (int p2 = 0; p2 < 4; ++p2) {
                int bb = bi[p2];
                unsigned r0 = lm[bb];         // pair (m[y,x], m[y,x+1])
                unsigned r1 = lm[bb + HWP];   // pair of row y+1, bank +4
                float vv = tap_dot(ua[p2], r0, tap_dot(ub[p2], r1, 0.f));
                if (sig) vv = fast_sigmoid(vv);
                v[p2] = vv;
            }
            ushort4_t o = {f2bf_t(v[0]), f2bf_t(v[1]), f2bf_t(v[2]), f2bf_t(v[3])};
            o4[q] = o;
            sum += (v[0] + v[1]) + (v[2] + v[3]);
        };

        #pragma unroll
        for (int it = 0; it < 3; ++it) {
            int q = it * SBLK + tid;
            if (q < nq) do_quad(idr[it], war[it], wbr[it], q);
        }
        if (ntail > 0 && ntail <= 64) {                       // balanced tail (1 per 16 lanes)
            int tq = tid >> 4;
            if (((tid & 15) == 0) && tq < ntail)
                do_quad(tmi4[tq], tma[tq], tmb[tq], 3 * SBLK + tq);
        }

        #pragma unroll
        for (int m2 = 32; m2 > 0; m2 >>= 1) sum += __shfl_xor(sum, m2, 64);
        if (lane == 0) wred[k & 1][tid >> 6] = sum;
        LDS_BARRIER();
        if (tid == 0) {
            float s = 0.f;
            #pragma unroll
            for (int w2 = 0; w2 < SBLK / 64; ++w2) s += wred[k & 1][w2];
            if (sig) ssum[mi] = s;
            else tsum[mi - N] = s;
        }
    }
}

// ---------- kernel 2: MFMA split-K GEMM: Cpart[ks][n][t] = sum_k S[n,k]*Tm[t,k] ----------
#define LDF(Aarr, Barr, kof)                                                              \
    do {                                                                                  \
        _Pragma("unroll") for (int m_ = 0; m_ < 3; ++m_)                                  \
            Aarr[m_] = *(const short8*)(pa + (size_t)m_ * 16 * P + (kof));                \
        _Pragma("unroll") for (int j_ = 0; j_ < 5; ++j_)                                  \
            Barr[j_] = *(const short8*)(pb + (size_t)j_ * 16 * P + (kof));                \
    } while (0)

#define FMAS(Aarr, Barr)                                                                  \
    do {                                                                                  \
        _Pragma("unroll") for (int m_ = 0; m_ < 3; ++m_) {                                \
            _Pragma("unroll") for (int j_ = 0; j_ < 5; ++j_)                              \
                acc[m_][j_] = __builtin_amdgcn_mfma_f32_16x16x32_bf16(                    \
                    Aarr[m_], Barr[j_], acc[m_][j_], 0, 0, 0);                            \
        }                                                                                 \
    } while (0)

__global__ __launch_bounds__(256) void kgemm(const ushort_t* __restrict__ S,
                                             const ushort_t* __restrict__ Tm,
                                             float* __restrict__ Cpart,
                                             const int* __restrict__ lvl,
                                             int N, int T, int P, int nsteps) {
    if (*lvl >= 2) return;
    int tid = threadIdx.x;
    int wid = tid >> 6, lane = tid & 63;
    int wm = wid >> 1, wt = wid & 1;
    int r = lane & 15, g = lane >> 4;
    int n0 = blockIdx.x * 96 + wm * 48;
    int t0 = wt * 80;
    size_t k0 = (size_t)blockIdx.y * nsteps * 32 + g * 8;
    const ushort_t* pa = S + (size_t)(n0 + r) * P + k0;
    const ushort_t* pb = Tm + (size_t)(t0 + r) * P + k0;

    f32x4 acc[3][5];
    #pragma unroll
    for (int m2 = 0; m2 < 3; ++m2)
        #pragma unroll
        for (int j2 = 0; j2 < 5; ++j2) acc[m2][j2] = (f32x4){0.f, 0.f, 0.f, 0.f};

    short8 a0[3], b0[5], a1[3], b1[5];
    LDF(a0, b0, 0);
    int ks = 0;
    for (; ks + 2 < nsteps; ks += 2) {
        LDF(a1, b1, (ks + 1) * 32);
        FMAS(a0, b0);
        LDF(a0, b0, (ks + 2) * 32);
        FMAS(a1, b1);
    }
    LDF(a1, b1, (ks + 1) * 32);
    FMAS(a0, b0);
    FMAS(a1, b1);

    size_t cb = (size_t)blockIdx.y * N * T;
    #pragma unroll
    for (int m2 = 0; m2 < 3; ++m2)
        #pragma unroll
        for (int j2 = 0; j2 < 5; ++j2)
            #pragma unroll
            for (int q = 0; q < 4; ++q) {
                int row = n0 + m2 * 16 + g * 4 + q;
                int col = t0 + j2 * 16 + r;
                Cpart[cb + (size_t)row * T + col] = acc[m2][j2][q];
            }
}

// ---------- kernel 3: epilogue ----------
__global__ void kfinal(const float* __restrict__ logits, const float* __restrict__ opts,
                       const float* __restrict__ tpts, const float* __restrict__ Cpart,
                       const float* __restrict__ ssum, const float* __restrict__ tsum,
                       const int* __restrict__ lvl, float* __restrict__ out,
                       int N, int T, int nks) {
    int idx = blockIdx.x * 256 + threadIdx.x;
    if (idx >= N * T) return;
    int n = idx / T, t = idx - n * T;

    float lg = logits[n];
    float p = 1.f / (1.f + __expf(-lg));
    float pos = 0.25f * (1.f - p) * (1.f - p) * (-logf(p + 1e-8f));
    float neg = 0.75f * p * p * (-logf(1.f - p + 1e-8f));
    float ccls = pos - neg;

    float kp = 0.f;
    const float4* a4 = (const float4*)(opts + (size_t)n * 32);
    const float4* b4 = (const float4*)(tpts + (size_t)t * 32);
    #pragma unroll
    for (int j = 0; j < 8; ++j) {
        float4 a = a4[j], b = b4[j];
        kp += fabsf(a.x - b.x) + fabsf(a.y - b.y) + fabsf(a.z - b.z) + fabsf(a.w - b.w);
    }

    float dice = 0.f;
    if (*lvl < 2) {
        float dot = 0.f;
        for (int ks = 0; ks < nks; ++ks) dot += Cpart[(size_t)ks * N * T + idx];
        dice = 1.f - (2.f * dot + 1.f) / (ssum[n] + tsum[t] + 1.f);
    }
    out[idx] = 2.f * ccls + 5.f * kp + 5.f * dice;
}

extern "C" void kernel_launch(void* const* d_in, const int* in_sizes, int n_in,
                              void* d_out, int out_size, void* d_ws, size_t ws_size,
                              hipStream_t stream) {
    const float* logits = (const float*)d_in[0];
    const float* cpts   = (const float*)d_in[1];
    const float* pmask  = (const float*)d_in[2];
    const float* tpts   = (const float*)d_in[3];
    const float* tmasks = (const float*)d_in[4];
    const float* coords = (const float*)d_in[5];
    const int*   lvl    = (const int*)d_in[6];
    float* out = (float*)d_out;

    int N = in_sizes[0];        // 2400
    int T = in_sizes[3] / 32;   // 160
    int P = in_sizes[5] / 2;    // 12544

    char* w = (char*)d_ws;
    auto alloc = [&](size_t bytes) {
        char* r = w;
        w += (bytes + 255) & ~(size_t)255;
        return r;
    };
    ushort_t* tsamp = (ushort_t*)alloc((size_t)T * P * 2);
    ushort_t* S     = (ushort_t*)alloc((size_t)N * P * 2);
    float*    ssumb = (float*)alloc((size_t)N * 4);
    float*    tsumb = (float*)alloc((size_t)T * 4);
    size_t base_bytes = (size_t)(w - (char*)d_ws);

    int nks = 14;
    if (base_bytes + (size_t)nks * N * T * 4 > ws_size) nks = 7;
    int nsteps = (P / 32) / nks;
    float* Cpart = (float*)alloc((size_t)nks * N * T * 4);

    ksamp_all<<<NBLK, SBLK, 0, stream>>>(pmask, tmasks, coords, S, tsamp,
                                         ssumb, tsumb, lvl, N, T, P);
    kgemm<<<dim3(N / 96, nks), 256, 0, stream>>>(S, tsamp, Cpart, lvl, N, T, P, nsteps);
    kfinal<<<(N * T + 255) / 256, 256, 0, stream>>>(logits, cpts, tpts, Cpart, ssumb, tsumb,
                                                    lvl, out, N, T, nks);
}

// Round 19
// 115.811 us; speedup vs baseline: 1.0449x; 1.0033x over previous
//
#include <hip/hip_runtime.h>
#include <hip/hip_bf16.h>
#include <cstdint>

#define HW 128
#define HWP 132                    // padded row stride (words): taps 4 banks apart, uint4-aligned writes
#define MASK_ELEMS (HW * HW)
#define TILE_WORDS (HW * HWP)      // 16896 words = 66KB per tile
#define SBLK 1024                  // sampler block size (16 waves)
#define NBLK 256                   // sampler grid (1 block/CU via ~135KB LDS)

typedef unsigned short ushort_t;
typedef __attribute__((ext_vector_type(4))) unsigned short ushort4_t;
typedef __attribute__((ext_vector_type(8))) short short8;
typedef __attribute__((ext_vector_type(4))) float f32x4;

__device__ __forceinline__ float asf(unsigned int u) {
    union { unsigned int i; float f; } c;
    c.i = u;
    return c.f;
}
__device__ __forceinline__ ushort_t f2bf(float f) {          // RNE (tile + weights)
    union { float f; unsigned int i; } c;
    c.f = f;
    unsigned int r = c.i + 0x7FFFu + ((c.i >> 16) & 1u);
    return (ushort_t)(r >> 16);
}
__device__ __forceinline__ ushort_t f2bf_t(float f) {        // truncating (outputs only)
    union { float f; unsigned int i; } c;
    c.f = f;
    return (ushort_t)(c.i >> 16);
}
__device__ __forceinline__ unsigned pack2(float a, float b) {
    return (unsigned)f2bf(a) | ((unsigned)f2bf(b) << 16);
}

// Minimal-op sigmoid: 1/(1+e^-v) = rcp(1 + 2^(v * -log2e))
#if __has_builtin(__builtin_amdgcn_exp2f)
__device__ __forceinline__ float fast_sigmoid(float v) {
    return __builtin_amdgcn_rcpf(1.f + __builtin_amdgcn_exp2f(v * -1.442695041f));
}
#else
__device__ __forceinline__ float fast_sigmoid(float v) {
    return __builtin_amdgcn_rcpf(1.f + __expf(-v));
}
#endif

// Packed-pair dot: w = (bf16 w0, bf16 w1), t = (bf16 t0, bf16 t1) -> c + w0*t0 + w1*t1.
#if __has_builtin(__builtin_amdgcn_fdot2_f32_bf16)
typedef __bf16 bf16x2_t __attribute__((ext_vector_type(2)));
__device__ __forceinline__ float tap_dot(unsigned w, unsigned t, float c) {
    return __builtin_amdgcn_fdot2_f32_bf16(__builtin_bit_cast(bf16x2_t, w),
                                           __builtin_bit_cast(bf16x2_t, t), c, false);
}
#else
__device__ __forceinline__ float tap_dot(unsigned w, unsigned t, float c) {
    return c + asf(w << 16) * asf(t << 16)
             + asf(w & 0xffff0000u) * asf(t & 0xffff0000u);
}
#endif

// LDS-visibility-only barrier: NO vmcnt drain (keeps stage loads in flight).
#define LDS_BARRIER()                                         \
    do {                                                      \
        asm volatile("s_waitcnt lgkmcnt(0)" ::: "memory");    \
        __builtin_amdgcn_s_barrier();                         \
    } while (0)

// Per-point bilinear setup: PADDED base b = by*132+bx (bx<=126, by<=126); taps are
// lm[b] (pair x,x+1 of row by) and lm[b+132] (pair of row by+1).
struct PMeta { int b; unsigned u0, u1; };
__device__ __forceinline__ PMeta prep_point(float cx, float cy) {
    float x = cx * (float)HW - 0.5f;
    float y = cy * (float)HW - 0.5f;
    float x0f = floorf(x), y0f = floorf(y);
    float wx1 = x - x0f, wy1 = y - y0f;
    float wx0 = 1.f - wx1, wy0 = 1.f - wy1;
    int x0 = (int)x0f, y0 = (int)y0f;
    float wxA = (x0 >= 0) ? wx0 : wx1;
    float wxB = (x0 >= 0 && x0 < HW - 1) ? wx1 : 0.f;
    float wyA = (y0 >= 0) ? wy0 : wy1;
    float wyB = (y0 >= 0 && y0 < HW - 1) ? wy1 : 0.f;
    int bx = max(x0, 0), by = max(y0, 0);
    if (bx > HW - 2) { bx = HW - 2; wxB = wxA; wxA = 0.f; }
    if (by > HW - 2) { by = HW - 2; wyB = wyA; wyA = 0.f; }
    PMeta m;
    m.b = by * HWP + bx;
    m.u0 = pack2(wxA * wyA, wxB * wyA);
    m.u1 = pack2(wxA * wyB, wxB * wyB);
    return m;
}

// ---------- kernel 1: persistent fused sampler (r18 + deferred reduce, 1 barrier/mask) ----
// The per-mask epilogue barrier is gone: wred[k&1] is written pre-barrier and folded by
// tid0 DURING the next iteration's sample phase (double-buffered; last mask after loop).
__global__ __launch_bounds__(SBLK) void ksamp_all(
        const float* __restrict__ pmask, const float* __restrict__ tmasks,
        const float* __restrict__ coords,
        ushort_t* __restrict__ S, ushort_t* __restrict__ tsamp,
        float* __restrict__ ssum, float* __restrict__ tsum,
        const int* __restrict__ lvl, int N, int T, int P) {
    if (*lvl >= 2) return;
    __shared__ unsigned buf[2][TILE_WORDS];  // 2 x 66KB padded packed-pair tiles
    __shared__ float wred[2][SBLK / 64];
    __shared__ int4  tmi4[64];               // tail-quad meta (3KB)
    __shared__ uint4 tma[64], tmb[64];
    const int tid = threadIdx.x;
    const int lane = tid & 63;
    const int NM = N + T;
    const int nq = P >> 2;
    const int ntail = nq - 3 * SBLK;         // 64 for P=12544

    // ---- dense meta: 3 quads/thread computed from coords (36 VGPR) ----
    int4 idr[3];
    uint4 war[3], wbr[3];
    #pragma unroll
    for (int it = 0; it < 3; ++it) {
        int q = it * SBLK + tid;
        if (q < nq) {
            float4 ca = ((const float4*)coords)[2 * q];
            float4 cb = ((const float4*)coords)[2 * q + 1];
            PMeta m0 = prep_point(ca.x, ca.y), m1 = prep_point(ca.z, ca.w);
            PMeta m2 = prep_point(cb.x, cb.y), m3 = prep_point(cb.z, cb.w);
            idr[it] = make_int4(m0.b, m1.b, m2.b, m3.b);
            war[it] = make_uint4(m0.u0, m0.u1, m1.u0, m1.u1);
            wbr[it] = make_uint4(m2.u0, m2.u1, m3.u0, m3.u1);
        } else {
            idr[it] = make_int4(0, 0, 0, 0);
            war[it] = make_uint4(0, 0, 0, 0);
            wbr[it] = make_uint4(0, 0, 0, 0);
        }
    }
    // ---- tail meta -> LDS (computed once; visible after first barrier) ----
    if (ntail > 0 && tid < ntail && tid < 64) {
        int q = 3 * SBLK + tid;
        float4 ca = ((const float4*)coords)[2 * q];
        float4 cb = ((const float4*)coords)[2 * q + 1];
        PMeta m0 = prep_point(ca.x, ca.y), m1 = prep_point(ca.z, ca.w);
        PMeta m2 = prep_point(cb.x, cb.y), m3 = prep_point(cb.z, cb.w);
        tmi4[tid] = make_int4(m0.b, m1.b, m2.b, m3.b);
        tma[tid] = make_uint4(m0.u0, m0.u1, m1.u0, m1.u1);
        tmb[tid] = make_uint4(m2.u0, m2.u1, m3.u0, m3.u1);
    }

    auto mptr = [&](int mi) -> const float* {
        return (mi < N) ? pmask + (size_t)mi * MASK_ELEMS
                        : tmasks + (size_t)(mi - N) * MASK_ELEMS;
    };
    auto emit_sum = [&](int mi, float s) {
        if (mi < N) ssum[mi] = s;
        else tsum[mi - N] = s;
    };

    const int b = blockIdx.x;
    const int rounds = (NM - b + NBLK - 1) / NBLK;   // 10 for NM=2560
    if (rounds <= 0) return;

    float4 rS[4];
    float nxr[4];                             // lane-63-only next-element values
    auto load_mask = [&](const float* g) {
        #pragma unroll
        for (int j = 0; j < 4; ++j) {
            int o = j * (SBLK * 4) + tid * 4;
            rS[j] = *(const float4*)(g + o);
            nxr[j] = (lane == 63) ? g[min(o + 4, MASK_ELEMS - 1)] : 0.f;
        }
    };
    auto pack_mask = [&](unsigned* l) {
        #pragma unroll
        for (int j = 0; j < 4; ++j) {
            int o = j * (SBLK * 4) + tid * 4;      // linear word index (4 words, one row)
            float4 v = rS[j];
            float nx = __shfl_down(v.x, 1);
            if (lane == 63) nx = nxr[j];
            int row = o >> 7, col = o & 127;
            uint4 e = make_uint4(pack2(v.x, v.y), pack2(v.y, v.z),
                                 pack2(v.z, v.w), pack2(v.w, nx));
            *(uint4*)&l[row * HWP + col] = e;      // 16B-aligned (132*row + col, col%4==0)
        }
    };

    load_mask(mptr(b));
    pack_mask(buf[0]);
    if (rounds > 1) load_mask(mptr(b + NBLK));

    for (int k = 0; k < rounds; ++k) {
        LDS_BARRIER();   // single barrier/mask: orders prev reads of buf[(k+1)&1] vs pack
                         // below, prev pack of buf[k&1] vs reads below, AND publishes
                         // wred[(k-1)&1] for the deferred reducer.
        if (k > 0 && tid == 0) {              // fold LAST mask's wave sums (off critical path)
            float s = 0.f;
            #pragma unroll
            for (int w2 = 0; w2 < SBLK / 64; ++w2) s += wred[(k - 1) & 1][w2];
            emit_sum(b + (k - 1) * NBLK, s);
        }
        if (k + 1 < rounds) {
            pack_mask(buf[(k + 1) & 1]);                      // mask k+1 -> other buffer
            if (k + 2 < rounds) load_mask(mptr(b + (k + 2) * NBLK));  // k+2 in flight
        }
        const unsigned* lm = buf[k & 1];
        const int mi = b + k * NBLK;
        const bool sig = (mi < N);
        ushort4_t* o4 = sig ? (ushort4_t*)(S + (size_t)mi * P)
                            : (ushort4_t*)(tsamp + (size_t)(mi - N) * P);
        float sum = 0.f;

        auto do_quad = [&](int4 id, uint4 wa4, uint4 wb4, int q) {
            float v[4];
            int bi[4] = {id.x, id.y, id.z, id.w};
            unsigned ua[4] = {wa4.x, wa4.z, wb4.x, wb4.z};
            unsigned ub[4] = {wa4.y, wa4.w, wb4.y, wb4.w};
            #pragma unroll
            for (int p2 = 0; p2 < 4; ++p2) {
                int bb = bi[p2];
                unsigned r0 = lm[bb];         // pair (m[y,x], m[y,x+1])
                unsigned r1 = lm[bb + HWP];   // pair of row y+1, bank +4
                float vv = tap_dot(ua[p2], r0, tap_dot(ub[p2], r1, 0.f));
                if (sig) vv = fast_sigmoid(vv);
                v[p2] = vv;
            }
            ushort4_t o = {f2bf_t(v[0]), f2bf_t(v[1]), f2bf_t(v[2]), f2bf_t(v[3])};
            o4[q] = o;
            sum += (v[0] + v[1]) + (v[2] + v[3]);
        };

        #pragma unroll
        for (int it = 0; it < 3; ++it) {
            int q = it * SBLK + tid;
            if (q < nq) do_quad(idr[it], war[it], wbr[it], q);
        }
        if (ntail > 0 && ntail <= 64) {                       // balanced tail (1 per 16 lanes)
            int tq = tid >> 4;
            if (((tid & 15) == 0) && tq < ntail)
                do_quad(tmi4[tq], tma[tq], tmb[tq], 3 * SBLK + tq);
        }

        #pragma unroll
        for (int m2 = 32; m2 > 0; m2 >>= 1) sum += __shfl_xor(sum, m2, 64);
        if (lane == 0) wred[k & 1][tid >> 6] = sum;           // folded next iter (or below)
    }
    // final mask's reduction (its wred writes are wave-local-complete; lgkmcnt orders them)
    asm volatile("s_waitcnt lgkmcnt(0)" ::: "memory");
    __builtin_amdgcn_s_barrier();
    if (tid == 0) {
        float s = 0.f;
        #pragma unroll
        for (int w2 = 0; w2 < SBLK / 64; ++w2) s += wred[(rounds - 1) & 1][w2];
        emit_sum(b + (rounds - 1) * NBLK, s);
    }
}

// ---------- kernel 2: MFMA split-K GEMM: Cpart[ks][n][t] = sum_k S[n,k]*Tm[t,k] ----------
#define LDF(Aarr, Barr, kof)                                                              \
    do {                                                                                  \
        _Pragma("unroll") for (int m_ = 0; m_ < 3; ++m_)                                  \
            Aarr[m_] = *(const short8*)(pa + (size_t)m_ * 16 * P + (kof));                \
        _Pragma("unroll") for (int j_ = 0; j_ < 5; ++j_)                                  \
            Barr[j_] = *(const short8*)(pb + (size_t)j_ * 16 * P + (kof));                \
    } while (0)

#define FMAS(Aarr, Barr)                                                                  \
    do {                                                                                  \
        _Pragma("unroll") for (int m_ = 0; m_ < 3; ++m_) {                                \
            _Pragma("unroll") for (int j_ = 0; j_ < 5; ++j_)                              \
                acc[m_][j_] = __builtin_amdgcn_mfma_f32_16x16x32_bf16(                    \
                    Aarr[m_], Barr[j_], acc[m_][j_], 0, 0, 0);                            \
        }                                                                                 \
    } while (0)

__global__ __launch_bounds__(256) void kgemm(const ushort_t* __restrict__ S,
                                             const ushort_t* __restrict__ Tm,
                                             float* __restrict__ Cpart,
                                             const int* __restrict__ lvl,
                                             int N, int T, int P, int nsteps) {
    if (*lvl >= 2) return;
    int tid = threadIdx.x;
    int wid = tid >> 6, lane = tid & 63;
    int wm = wid >> 1, wt = wid & 1;
    int r = lane & 15, g = lane >> 4;
    int n0 = blockIdx.x * 96 + wm * 48;
    int t0 = wt * 80;
    size_t k0 = (size_t)blockIdx.y * nsteps * 32 + g * 8;
    const ushort_t* pa = S + (size_t)(n0 + r) * P + k0;
    const ushort_t* pb = Tm + (size_t)(t0 + r) * P + k0;

    f32x4 acc[3][5];
    #pragma unroll
    for (int m2 = 0; m2 < 3; ++m2)
        #pragma unroll
        for (int j2 = 0; j2 < 5; ++j2) acc[m2][j2] = (f32x4){0.f, 0.f, 0.f, 0.f};

    short8 a0[3], b0[5], a1[3], b1[5];
    LDF(a0, b0, 0);
    int ks = 0;
    for (; ks + 2 < nsteps; ks += 2) {
        LDF(a1, b1, (ks + 1) * 32);
        FMAS(a0, b0);
        LDF(a0, b0, (ks + 2) * 32);
        FMAS(a1, b1);
    }
    LDF(a1, b1, (ks + 1) * 32);
    FMAS(a0, b0);
    FMAS(a1, b1);

    size_t cb = (size_t)blockIdx.y * N * T;
    #pragma unroll
    for (int m2 = 0; m2 < 3; ++m2)
        #pragma unroll
        for (int j2 = 0; j2 < 5; ++j2)
            #pragma unroll
            for (int q = 0; q < 4; ++q) {
                int row = n0 + m2 * 16 + g * 4 + q;
                int col = t0 + j2 * 16 + r;
                Cpart[cb + (size_t)row * T + col] = acc[m2][j2][q];
            }
}

// ---------- kernel 3: epilogue ----------
__global__ void kfinal(const float* __restrict__ logits, const float* __restrict__ opts,
                       const float* __restrict__ tpts, const float* __restrict__ Cpart,
                       const float* __restrict__ ssum, const float* __restrict__ tsum,
                       const int* __restrict__ lvl, float* __restrict__ out,
                       int N, int T, int nks) {
    int idx = blockIdx.x * 256 + threadIdx.x;
    if (idx >= N * T) return;
    int n = idx / T, t = idx - n * T;

    float lg = logits[n];
    float p = 1.f / (1.f + __expf(-lg));
    float pos = 0.25f * (1.f - p) * (1.f - p) * (-logf(p + 1e-8f));
    float neg = 0.75f * p * p * (-logf(1.f - p + 1e-8f));
    float ccls = pos - neg;

    float kp = 0.f;
    const float4* a4 = (const float4*)(opts + (size_t)n * 32);
    const float4* b4 = (const float4*)(tpts + (size_t)t * 32);
    #pragma unroll
    for (int j = 0; j < 8; ++j) {
        float4 a = a4[j], b = b4[j];
        kp += fabsf(a.x - b.x) + fabsf(a.y - b.y) + fabsf(a.z - b.z) + fabsf(a.w - b.w);
    }

    float dice = 0.f;
    if (*lvl < 2) {
        float dot = 0.f;
        for (int ks = 0; ks < nks; ++ks) dot += Cpart[(size_t)ks * N * T + idx];
        dice = 1.f - (2.f * dot + 1.f) / (ssum[n] + tsum[t] + 1.f);
    }
    out[idx] = 2.f * ccls + 5.f * kp + 5.f * dice;
}

extern "C" void kernel_launch(void* const* d_in, const int* in_sizes, int n_in,
                              void* d_out, int out_size, void* d_ws, size_t ws_size,
                              hipStream_t stream) {
    const float* logits = (const float*)d_in[0];
    const float* cpts   = (const float*)d_in[1];
    const float* pmask  = (const float*)d_in[2];
    const float* tpts   = (const float*)d_in[3];
    const float* tmasks = (const float*)d_in[4];
    const float* coords = (const float*)d_in[5];
    const int*   lvl    = (const int*)d_in[6];
    float* out = (float*)d_out;

    int N = in_sizes[0];        // 2400
    int T = in_sizes[3] / 32;   // 160
    int P = in_sizes[5] / 2;    // 12544

    char* w = (char*)d_ws;
    auto alloc = [&](size_t bytes) {
        char* r = w;
        w += (bytes + 255) & ~(size_t)255;
        return r;
    };
    ushort_t* tsamp = (ushort_t*)alloc((size_t)T * P * 2);
    ushort_t* S     = (ushort_t*)alloc((size_t)N * P * 2);
    float*    ssumb = (float*)alloc((size_t)N * 4);
    float*    tsumb = (float*)alloc((size_t)T * 4);
    size_t base_bytes = (size_t)(w - (char*)d_ws);

    int nks = 14;
    if (base_bytes + (size_t)nks * N * T * 4 > ws_size) nks = 7;
    int nsteps = (P / 32) / nks;
    float* Cpart = (float*)alloc((size_t)nks * N * T * 4);

    ksamp_all<<<NBLK, SBLK, 0, stream>>>(pmask, tmasks, coords, S, tsamp,
                                         ssumb, tsumb, lvl, N, T, P);
    kgemm<<<dim3(N / 96, nks), 256, 0, stream>>>(S, tsamp, Cpart, lvl, N, T, P, nsteps);
    kfinal<<<(N * T + 255) / 256, 256, 0, stream>>>(logits, cpts, tpts, Cpart, ssumb, tsumb,
                                                    lvl, out, N, T, nks);
}